// Round 1
// baseline (117.930 us; speedup 1.0000x reference)
//
#include <hip/hip_runtime.h>

#define B_AGENTS 262144
#define NN 17

__global__ __launch_bounds__(256) void grossberg_kernel(
    const float* __restrict__ state,
    const float* __restrict__ W_pos,
    const float* __restrict__ W_neg,
    const float* __restrict__ feas,
    const float* __restrict__ pert,
    float* __restrict__ out)
{
    const int t = blockIdx.x * blockDim.x + threadIdx.x;
    const int total = B_AGENTS * NN;
    if (t >= total) return;

    const int b = t / NN;            // magic-multiply
    const int i = t - b * NN;

    // --- load this agent's state vector (L1-shared across the agent's 17 threads)
    const float* __restrict__ s = state + b * NN;
    float sv[NN];
    #pragma unroll
    for (int j = 0; j < NN; ++j) sv[j] = s[j];

    // --- two matvec rows, contiguous 68 B each
    const float* __restrict__ wp = W_pos + (size_t)b * (NN * NN) + i * NN;
    const float* __restrict__ wn = W_neg + (size_t)b * (NN * NN) + i * NN;
    float sum_p = 0.f, sum_n = 0.f;
    #pragma unroll
    for (int j = 0; j < NN; ++j) {
        sum_p = fmaf(wp[j], sv[j], sum_p);
        sum_n = fmaf(wn[j], sv[j], sum_n);
    }

    // --- gating / env / lateral / mask
    float gate_e = 1.f, gate_i = 1.f;
    float env_e = 0.f, env_i = 0.f;
    float lat = 0.f, mask = 1.f;

    if (i < 9) {
        const float p = pert[b * NN + i];
        env_e = fmaxf(p, 0.f);
        env_i = fmaxf(-p, 0.f);
    } else if (i < 13) {
        const float v = sv[i + 4] + pert[b * NN + i + 4];   // valences_eval[i-9]
        gate_e = 1.f / (1.f + __expf(-1.5f * v));           // sigmoid(ALPHA*v)
        gate_i = 1.f / (1.f + __expf(0.75f * v));           // sigmoid(-BETA*v)
        const float sum_act = sv[9] + sv[10] + sv[11] + sv[12];
        const float other = sum_act - sv[i];
        lat = 3.0f * other / (0.3f + other + 1e-6f);        // LAT_INHIB, DIV_SIGMA
        mask = feas[b * 4 + (i - 9)];
    }

    const float te = gate_e * sum_p + env_e;                // total excitation
    const float ti = gate_i * sum_n + lat + env_i;          // total inhibition
    const float si = sv[i];

    // dS/dt = (-DECAY*s + (B_CAP - s)*relu(te) - (C_FLOOR + s)*relu(ti)) / TAU
    const float dS = (-0.15f * si
                      + (1.0f - si) * fmaxf(te, 0.f)
                      - (0.1f + si) * fmaxf(ti, 0.f)) * 1.25f;

    out[t] = dS * mask;
}

extern "C" void kernel_launch(void* const* d_in, const int* in_sizes, int n_in,
                              void* d_out, int out_size, void* d_ws, size_t ws_size,
                              hipStream_t stream)
{
    // setup_inputs order: t, state, W_pos, W_neg, feasibility, perturbation
    const float* state = (const float*)d_in[1];
    const float* W_pos = (const float*)d_in[2];
    const float* W_neg = (const float*)d_in[3];
    const float* feas  = (const float*)d_in[4];
    const float* pert  = (const float*)d_in[5];
    float* out = (float*)d_out;

    const int total = B_AGENTS * NN;
    const int block = 256;
    const int grid = (total + block - 1) / block;
    grossberg_kernel<<<grid, block, 0, stream>>>(state, W_pos, W_neg, feas, pert, out);
}